// Round 13
// baseline (1024.423 us; speedup 1.0000x reference)
//
#include <hip/hip_runtime.h>
#include <hip/hip_bf16.h>
#include <math.h>

#define NN 2048           // x is 2048 x 2048 (DP grid = [0,2046]^2)
#define TROWS 1040        // table rows per half (1024 + prefetch margin)
#define NW 8              // 8 waves per WG (2 per SIMD), CPL=4
#define RPS 32            // rows per wave per step; 32-row rescale cadence:
                          // max growth ~57 nats << 88 (see R13 analysis; R3's
                          // overflow was 64 rows ~105 nats; 16 rows proven R5-R12)
#define LN2 0.6931471805599453

// d_ws layout (floats): tab[TROWS][NN] | tabR[TROWS][NN] | arr: S,tg,yc,gM,gY (5*NN) | res (4 words)

// ---------------------------------------------------------------------------
// Prologue: tab[t][c] = exp(x[t][c]); tabR[t][c] = exp(x[2048-t][2048-c]) or 0
// when OOB -- the column-mirrored, row-reversed table for the adjoint sweep.
// ---------------------------------------------------------------------------
__global__ void prep_kernel(const float* __restrict__ x, float* __restrict__ tab,
                            float* __restrict__ tabR) {
  const int c = blockIdx.x * 256 + threadIdx.x;
  const int t = blockIdx.y;
  tab[(size_t)t * NN + c] = __expf(x[(size_t)t * NN + c]);
  const int rr = 2048 - t, cc = 2048 - c;
  float v = 0.f;
  if (rr < 2048 && cc < 2048) v = __expf(x[(size_t)rr * NN + cc]);
  tabR[(size_t)t * NN + c] = v;
}

// ---------------------------------------------------------------------------
// MODE 1, blockIdx 0: FORWARD top half (rows 0..1023). 8 waves, 4 cols/lane,
//   systolic skew (wave w does rows 32(s-w)..+31 at step s), parity LDS edges
//   {S, X'}, one barrier + one shared pow2 exponent per 32 rows, 4-deep VMEM
//   prefetch. X' via CPL4 Q-trick (2 shuffles, e^-8 truncation, R6-proven).
//   Ends writing boundary S, cGO*T, Y at row 1023 + acc_top, E0.
// MODE 1, blockIdx 1: BACKWARD adjoint of rows 2047->1024, column-mirrored
//   clone (alpha = es*(gM_diag+one); gY/gTs column recs; same Q-trick scan;
//   accB += es*gM; epilogue row 1024). Ends writing gM, gY at row 1024 + E1.
// MODE 0: fallback single-WG full sweep reading x directly.
// ---------------------------------------------------------------------------
template<int MODE>
__global__ __launch_bounds__(NW * 64)
void sw2_kernel(const float* __restrict__ x, const float* __restrict__ tab,
                const float* __restrict__ tabR, float* __restrict__ arr,
                float* __restrict__ out) {
  const int tid  = threadIdx.x;
  const int lane = tid & 63;
  const int wv   = __builtin_amdgcn_readfirstlane(tid >> 6);   // 0..7
  const int c0   = (wv << 8) + lane * 4;

  __shared__ float2 E[2][NW + 1][RPS];   // [parity][wave+1][row]; wave-0 input = zeros
  __shared__ float  red[2][NW];
  __shared__ float  wsum[NW];

  for (int i = tid; i < 2 * (NW + 1) * RPS; i += NW * 64)
    ((float2*)E)[i] = make_float2(0.f, 0.f);
  __syncthreads();

  const float cGO = 0.006737946999085467f;   // e^-5
  const float cGE = 0.36787944117144233f;    // e^-1
  const float C4  = 0.01831563888873418f;    // e^-4
  const bool isL0 = (lane == 0), isL1 = (lane == 1), isL63 = (lane == 63);

  if (MODE == 0 || blockIdx.x == 0) {
    // ======================= FORWARD =======================
    const int SPW   = ((MODE == 0) ? 2048 : 1024) / RPS;
    const int NSTEP = SPW + NW - 1;
    float s1_0=0.f,s1_1=0.f,s1_2=0.f,s1_3=0.f;
    float tg0=0.f,tg1=0.f,tg2=0.f,tg3=0.f;
    float yc0=0.f,yc1=0.f,yc2=0.f,yc3=0.f;
    float acc=0.f, one=1.f, tmx=0.f, escale=1.f, SinC=0.f;
    int Etot = 0;
    const float* src = ((MODE == 0) ? x : tab) + c0;
    float4 pf[4];
    pf[0] = *(const float4*)(src);
    pf[1] = *(const float4*)(src + NN);
    pf[2] = *(const float4*)(src + 2 * NN);
    pf[3] = *(const float4*)(src + 3 * NN);
    const float* pl = src + 4 * NN;
    int rown = 4;

    for (int s = 0; s < NSTEP; ++s) {
      const int pr = s & 1, cr = pr ^ 1;
      const bool act = (s >= wv) && (s < wv + SPW);
      if (act) {
        float prevEdx = 0.f;
        #pragma unroll
        for (int k = 0; k < RPS; ++k) {
          float4 ev = pf[k & 3];
          if (MODE == 1) { pf[k & 3] = *(const float4*)pl; pl += NN; }
          else { int rr = (rown < NN) ? rown : NN - 1; pf[k & 3] = *(const float4*)(src + (size_t)rr * NN); rown++; }
          float ex0 = ev.x, ex1 = ev.y, ex2 = ev.z, ex3 = ev.w;
          if (MODE == 0) { ex0 = __expf(ex0); ex1 = __expf(ex1); ex2 = __expf(ex2); ex3 = __expf(ex3); }

          const float2 edc = E[cr][wv][k];
          const float Sr = (k == 0) ? SinC : prevEdx * escale;
          const float Xi = edc.y * escale;
          prevEdx = edc.x;

          float sh  = __shfl_up(s1_3, 1);
          float sd0 = isL0 ? Sr : sh;
          acc = fmaf(ex0, sd0,  acc);
          acc = fmaf(ex1, s1_0, acc);
          acc = fmaf(ex2, s1_1, acc);
          acc = fmaf(ex3, s1_2, acc);
          float M0 = ex0 * (sd0  + one);
          float M1 = ex1 * (s1_0 + one);
          float M2 = ex2 * (s1_1 + one);
          float M3 = ex3 * (s1_2 + one);

          float Q  = fmaf(cGE, fmaf(cGE, fmaf(cGE, M0, M1), M2), M3);
          float q1 = __shfl_up(Q, 1);
          float q2 = __shfl_up(Q, 2);
          q2 = isL1 ? Xi : q2;
          float X0 = fmaf(C4, q2, q1);
          X0 = isL0 ? Xi : X0;
          float X1 = fmaf(cGE, X0, M0);
          float X2 = fmaf(cGE, X1, M1);
          float X3 = fmaf(cGE, X2, M2);

          float T0 = fmaf(cGO, X0, M0);
          float T1 = fmaf(cGO, X1, M1);
          float T2 = fmaf(cGO, X2, M2);
          float T3 = fmaf(cGO, X3, M3);
          float Y0 = fmaf(cGE, yc0, tg0);
          float Y1 = fmaf(cGE, yc1, tg1);
          float Y2 = fmaf(cGE, yc2, tg2);
          float Y3 = fmaf(cGE, yc3, tg3);
          float S0 = T0 + Y0, S1n = T1 + Y1, S2n = T2 + Y2, S3n = T3 + Y3;
          tmx = fmaxf(tmx, fmaxf(fmaxf(S0, S1n), fmaxf(S2n, S3n)));
          tg0 = cGO * T0; tg1 = cGO * T1; tg2 = cGO * T2; tg3 = cGO * T3;
          yc0 = Y0; yc1 = Y1; yc2 = Y2; yc3 = Y3;
          s1_0 = S0; s1_1 = S1n; s1_2 = S2n; s1_3 = S3n;

          if (isL63) E[pr][wv + 1][k] = make_float2(S3n, fmaf(C4, X0, Q));
        }
        SinC = prevEdx * escale;
      }
      { // per-step shared-exponent rescale (32 rows)
        float m = tmx;
        m = fmaxf(m, __shfl_xor(m, 1));  m = fmaxf(m, __shfl_xor(m, 2));
        m = fmaxf(m, __shfl_xor(m, 4));  m = fmaxf(m, __shfl_xor(m, 8));
        m = fmaxf(m, __shfl_xor(m, 16)); m = fmaxf(m, __shfl_xor(m, 32));
        if (lane == 0) red[pr][wv] = m;
      }
      __syncthreads();
      {
        float mm = red[pr][lane & (NW - 1)];
        mm = fmaxf(mm, __shfl_xor(mm, 1));
        mm = fmaxf(mm, __shfl_xor(mm, 2));
        mm = fmaxf(mm, __shfl_xor(mm, 4));
        tmx = 0.f; escale = 1.f;
        int e = (mm > 0.f) ? ilogbf(mm) : 0;
        if (e > 126) e = 126; if (e < -126) e = -126;
        if (e != 0) {
          const float c = ldexpf(1.f, -e);
          s1_0*=c; s1_1*=c; s1_2*=c; s1_3*=c;
          tg0*=c; tg1*=c; tg2*=c; tg3*=c;
          yc0*=c; yc1*=c; yc2*=c; yc3*=c;
          acc*=c; one*=c; SinC*=c;
          escale = c; Etot += e;
        }
      }
    }
    float ssum = acc;
    ssum += __shfl_xor(ssum, 1);  ssum += __shfl_xor(ssum, 2);
    ssum += __shfl_xor(ssum, 4);  ssum += __shfl_xor(ssum, 8);
    ssum += __shfl_xor(ssum, 16); ssum += __shfl_xor(ssum, 32);
    if (lane == 0) wsum[wv] = ssum;
    __syncthreads();
    if (MODE == 0) {
      if (tid == 0) {
        double tot = 0.0;
        #pragma unroll
        for (int k = 0; k < NW; ++k) tot += (double)wsum[k];
        out[0] = (float)(log(tot) + (double)Etot * LN2);
      }
    } else {
      *(float4*)(arr + c0)          = make_float4(s1_0, s1_1, s1_2, s1_3);  // S[1023,b]
      *(float4*)(arr + NN + c0)     = make_float4(tg0, tg1, tg2, tg3);      // cGO*T[1023,b]
      *(float4*)(arr + 2 * NN + c0) = make_float4(yc0, yc1, yc2, yc3);      // Y[1023,b]
      if (tid == 0) {
        float t = 0.f;
        #pragma unroll
        for (int k = 0; k < NW; ++k) t += wsum[k];
        arr[5 * NN + 0] = t;                     // acc_top (units 2^E0)
        ((int*)(arr + 5 * NN))[2] = Etot;        // E0
      }
    }
  } else {
    // ======================= BACKWARD (adjoint, mirrored cols) =======================
    const int SPWB = 1024 / RPS;                 // 32 active steps
    float gM1_0=0.f,gM1_1=0.f,gM1_2=0.f,gM1_3=0.f;
    float gY1_0=0.f,gY1_1=0.f,gY1_2=0.f,gY1_3=0.f;
    float accB=0.f, one=1.f, tmx=0.f, escale=1.f, gMinC=0.f;
    int Etot = 0;
    const float* src = tabR + c0;
    float4 pf[4];
    pf[0] = *(const float4*)(src);
    pf[1] = *(const float4*)(src + NN);
    pf[2] = *(const float4*)(src + 2 * NN);
    pf[3] = *(const float4*)(src + 3 * NN);
    const float* pl = src + 4 * NN;

    const int NSTEPB = SPWB + NW - 1 + 1;        // +1: epilogue row (es row 1024)
    for (int s = 0; s < NSTEPB; ++s) {
      const int pr = s & 1, cr = pr ^ 1;
      const bool actM = (s >= wv) && (s < wv + SPWB);
      const bool actE = (s == wv + SPWB);
      if (actM) {
        float prevEdx = 0.f;
        #pragma unroll
        for (int k = 0; k < RPS; ++k) {
          float4 ev = pf[k & 3];
          pf[k & 3] = *(const float4*)pl; pl += NN;
          const float er0 = ev.x, er1 = ev.y, er2 = ev.z, er3 = ev.w;

          const float2 edc = E[cr][wv][k];
          const float gMdIn = (k == 0) ? gMinC : prevEdx * escale;
          const float Xi = edc.y * escale;
          prevEdx = edc.x;

          float gmh  = __shfl_up(gM1_3, 1);
          float gMd0 = isL0 ? gMdIn : gmh;
          float gMd1 = gM1_0, gMd2 = gM1_1, gMd3 = gM1_2;
          accB = fmaf(er0, gMd0, accB);
          accB = fmaf(er1, gMd1, accB);
          accB = fmaf(er2, gMd2, accB);
          accB = fmaf(er3, gMd3, accB);
          float a0 = er0 * (gMd0 + one);
          float a1 = er1 * (gMd1 + one);
          float a2 = er2 * (gMd2 + one);
          float a3 = er3 * (gMd3 + one);

          float gTs0 = fmaf(cGO, gY1_0, a0);
          float gTs1 = fmaf(cGO, gY1_1, a1);
          float gTs2 = fmaf(cGO, gY1_2, a2);
          float gTs3 = fmaf(cGO, gY1_3, a3);
          float gY0n = fmaf(cGE, gY1_0, a0);
          float gY1n = fmaf(cGE, gY1_1, a1);
          float gY2n = fmaf(cGE, gY1_2, a2);
          float gY3n = fmaf(cGE, gY1_3, a3);

          float Qg = fmaf(cGE, fmaf(cGE, fmaf(cGE, gTs0, gTs1), gTs2), gTs3);
          float q1 = __shfl_up(Qg, 1);
          float q2 = __shfl_up(Qg, 2);
          q2 = isL1 ? Xi : q2;
          float gXin = fmaf(C4, q2, q1);
          gXin = isL0 ? Xi : gXin;
          float gX0 = fmaf(cGE, gXin, gTs0);
          float gX1 = fmaf(cGE, gX0,  gTs1);
          float gX2 = fmaf(cGE, gX1,  gTs2);
          float gM0n = fmaf(cGO, gXin, gTs0);
          float gM1n = fmaf(cGO, gX0,  gTs1);
          float gM2n = fmaf(cGO, gX1,  gTs2);
          float gM3n = fmaf(cGO, gX2,  gTs3);

          tmx = fmaxf(tmx, fmaxf(fmaxf(gM0n, gM1n), fmaxf(gM2n, gM3n)));
          tmx = fmaxf(tmx, fmaxf(fmaxf(gY0n, gY1n), fmaxf(gY2n, gY3n)));
          gM1_0 = gM0n; gM1_1 = gM1n; gM1_2 = gM2n; gM1_3 = gM3n;
          gY1_0 = gY0n; gY1_1 = gY1n; gY1_2 = gY2n; gY1_3 = gY3n;

          if (isL63) E[pr][wv + 1][k] = make_float2(gM3n, fmaf(C4, gXin, Qg));
        }
        gMinC = prevEdx * escale;
      } else if (actE) {
        // epilogue: accB += es[1024,.] * gM[1024,.]  (tabR row 1024 = pf[0])
        float gmh  = __shfl_up(gM1_3, 1);
        float gMd0 = isL0 ? gMinC : gmh;
        accB = fmaf(pf[0].x, gMd0,  accB);
        accB = fmaf(pf[0].y, gM1_0, accB);
        accB = fmaf(pf[0].z, gM1_1, accB);
        accB = fmaf(pf[0].w, gM1_2, accB);
      }
      { // rescale (carries stay live to the end)
        float m = tmx;
        m = fmaxf(m, __shfl_xor(m, 1));  m = fmaxf(m, __shfl_xor(m, 2));
        m = fmaxf(m, __shfl_xor(m, 4));  m = fmaxf(m, __shfl_xor(m, 8));
        m = fmaxf(m, __shfl_xor(m, 16)); m = fmaxf(m, __shfl_xor(m, 32));
        if (lane == 0) red[pr][wv] = m;
      }
      __syncthreads();
      {
        float mm = red[pr][lane & (NW - 1)];
        mm = fmaxf(mm, __shfl_xor(mm, 1));
        mm = fmaxf(mm, __shfl_xor(mm, 2));
        mm = fmaxf(mm, __shfl_xor(mm, 4));
        tmx = 0.f; escale = 1.f;
        int e = (mm > 0.f) ? ilogbf(mm) : 0;
        if (e > 126) e = 126; if (e < -126) e = -126;
        if (e != 0) {
          const float c = ldexpf(1.f, -e);
          gM1_0*=c; gM1_1*=c; gM1_2*=c; gM1_3*=c;
          gY1_0*=c; gY1_1*=c; gY1_2*=c; gY1_3*=c;
          accB*=c; one*=c; gMinC*=c;
          escale = c; Etot += e;
        }
      }
    }
    // write gM[1024,b], gY[1024,b]  (b = 2047-c -> reversed float4)
    *(float4*)(arr + 3 * NN + (2044 - c0)) = make_float4(gM1_3, gM1_2, gM1_1, gM1_0);
    *(float4*)(arr + 4 * NN + (2044 - c0)) = make_float4(gY1_3, gY1_2, gY1_1, gY1_0);
    float ssum = accB;
    ssum += __shfl_xor(ssum, 1);  ssum += __shfl_xor(ssum, 2);
    ssum += __shfl_xor(ssum, 4);  ssum += __shfl_xor(ssum, 8);
    ssum += __shfl_xor(ssum, 16); ssum += __shfl_xor(ssum, 32);
    if (lane == 0) wsum[wv] = ssum;
    __syncthreads();
    if (tid == 0) {
      float t = 0.f;
      #pragma unroll
      for (int k = 0; k < NW; ++k) t += wsum[k];
      arr[5 * NN + 1] = t;                       // acc_b0 (units 2^E1)
      ((int*)(arr + 5 * NN))[3] = Etot;          // E1
    }
  }
}

// ---------------------------------------------------------------------------
// Combine (unchanged): three exponent groups
//   A0 (2^E0) = acc_top + sum_b es[1024,b+1]*S[1023,b] ;  A1 (2^E1) = acc_b0
//   A01 (2^E0+E1) = sum_b es[1024,b+1]*gM[1024,b+1]*S[1023,b]
//                 + sum_b gY[1024,b]*(cGO*T[1023,b] + cGE*Y[1023,b])
// ---------------------------------------------------------------------------
__global__ __launch_bounds__(1024)
void combine_kernel(const float* __restrict__ tab, const float* __restrict__ arr,
                    float* __restrict__ out) {
  __shared__ double sh01[16], sh0[16];
  const int tid = threadIdx.x, lane = tid & 63, wv = tid >> 6;
  const float cGE = 0.36787944117144233f;
  double t01 = 0.0, t0 = 0.0;
  for (int b = tid; b < NN; b += 1024) {
    const float S  = arr[b];
    const float tg = arr[NN + b];
    const float yc = arr[2 * NN + b];
    const float gY = arr[4 * NN + b];
    t01 += (double)gY * ((double)tg + (double)cGE * (double)yc);
    if (b < NN - 1) {
      const float es = tab[(size_t)1024 * NN + b + 1];
      const float gM = arr[3 * NN + b + 1];
      t01 += (double)es * (double)gM * (double)S;
      t0  += (double)es * (double)S;
    }
  }
  #pragma unroll
  for (int off = 1; off < 64; off <<= 1) {
    t01 += __shfl_xor(t01, off);
    t0  += __shfl_xor(t0, off);
  }
  if (lane == 0) { sh01[wv] = t01; sh0[wv] = t0; }
  __syncthreads();
  if (tid == 0) {
    double A01 = 0.0, A0 = 0.0;
    #pragma unroll
    for (int k = 0; k < 16; ++k) { A01 += sh01[k]; A0 += sh0[k]; }
    const float* resF = arr + 5 * NN;
    const float accTop = resF[0], accB = resF[1];
    const int E0 = ((const int*)resF)[2], E1 = ((const int*)resF)[3];
    A0 += (double)accTop;
    const double A1 = (double)accB;
    const long long e01 = (long long)E0 + (long long)E1;
    long long em = e01;
    if ((long long)E0 > em) em = E0;
    if ((long long)E1 > em) em = E1;
    const double tot = A01 * exp2((double)(e01 - em))
                     + A0  * exp2((double)((long long)E0 - em))
                     + A1  * exp2((double)((long long)E1 - em));
    out[0] = (float)(log(tot) + (double)em * LN2);
  }
}

extern "C" void kernel_launch(void* const* d_in, const int* in_sizes, int n_in,
                              void* d_out, int out_size, void* d_ws, size_t ws_size,
                              hipStream_t stream) {
  const float* x = (const float*)d_in[0];
  float* out = (float*)d_out;
  const size_t need = ((size_t)2 * TROWS * NN + 5 * NN + 16) * sizeof(float);
  if (ws_size >= need) {
    float* tab  = (float*)d_ws;
    float* tabR = tab + (size_t)TROWS * NN;
    float* arr  = tab + (size_t)2 * TROWS * NN;
    prep_kernel<<<dim3(NN / 256, TROWS), dim3(256), 0, stream>>>(x, tab, tabR);
    sw2_kernel<1><<<dim3(2), dim3(NW * 64), 0, stream>>>(x, tab, tabR, arr, out);
    combine_kernel<<<dim3(1), dim3(1024), 0, stream>>>(tab, arr, out);
  } else {
    sw2_kernel<0><<<dim3(1), dim3(NW * 64), 0, stream>>>(x, nullptr, nullptr, nullptr, out);
  }
}

// Round 14
// 265.292 us; speedup vs baseline: 3.8615x; 3.8615x over previous
//
#include <hip/hip_runtime.h>
#include <hip/hip_bf16.h>
#include <math.h>

#define NN 2048           // x is 2048 x 2048 (DP grid = [0,2046]^2)
#define TROWS 1040        // table rows per half (1024 + prefetch margin)
#define NW 8              // 8 waves per WG (2 per SIMD), CPL=4
#define RPS 32            // rows per wave per step; 32-row rescale cadence:
                          // max growth ~57 nats << 88 (R3's overflow was 64 rows)
#define LN2 0.6931471805599453

// d_ws layout (floats): tab[TROWS][NN] | tabR[TROWS][NN] | arr: S,tg,yc,gM,gY (5*NN) | res (4 words)

__global__ void prep_kernel(const float* __restrict__ x, float* __restrict__ tab,
                            float* __restrict__ tabR) {
  const int c = blockIdx.x * 256 + threadIdx.x;
  const int t = blockIdx.y;
  tab[(size_t)t * NN + c] = __expf(x[(size_t)t * NN + c]);
  const int rr = 2048 - t, cc = 2048 - c;
  float v = 0.f;
  if (rr < 2048 && cc < 2048) v = __expf(x[(size_t)rr * NN + cc]);
  tabR[(size_t)t * NN + c] = v;
}

// ---------------------------------------------------------------------------
// R14 = R12's proven structure at RPS=32 with SPILL-PROOF codegen: the R13
// regression was rule-#20 scratch spill (pf[k&3] runtime-indexed register
// array when the 32-deep unroll was refused; WRITE_SIZE 58->810 MB). Here the
// inner loop is 8 groups x 4 rows with NAMED prefetch registers pfA..pfD and
// a per-row lambda -- no register array anywhere, any unroll decision is safe.
// ---------------------------------------------------------------------------
template<int MODE>
__global__ __launch_bounds__(NW * 64)
void sw2_kernel(const float* __restrict__ x, const float* __restrict__ tab,
                const float* __restrict__ tabR, float* __restrict__ arr,
                float* __restrict__ out) {
  const int tid  = threadIdx.x;
  const int lane = tid & 63;
  const int wv   = __builtin_amdgcn_readfirstlane(tid >> 6);   // 0..7
  const int c0   = (wv << 8) + lane * 4;

  __shared__ float2 E[2][NW + 1][RPS];   // [parity][wave+1][row]; wave-0 input = zeros
  __shared__ float  red[2][NW];
  __shared__ float  wsum[NW];

  for (int i = tid; i < 2 * (NW + 1) * RPS; i += NW * 64)
    ((float2*)E)[i] = make_float2(0.f, 0.f);
  __syncthreads();

  const float cGO = 0.006737946999085467f;   // e^-5
  const float cGE = 0.36787944117144233f;    // e^-1
  const float C4  = 0.01831563888873418f;    // e^-4
  const bool isL0 = (lane == 0), isL1 = (lane == 1), isL63 = (lane == 63);

  if (MODE == 0 || blockIdx.x == 0) {
    // ======================= FORWARD =======================
    const int SPW   = ((MODE == 0) ? 2048 : 1024) / RPS;
    const int NSTEP = SPW + NW - 1;
    float s1_0=0.f,s1_1=0.f,s1_2=0.f,s1_3=0.f;
    float tg0=0.f,tg1=0.f,tg2=0.f,tg3=0.f;
    float yc0=0.f,yc1=0.f,yc2=0.f,yc3=0.f;
    float acc=0.f, one=1.f, tmx=0.f, escale=1.f, SinC=0.f;
    int Etot = 0;
    const float* src = ((MODE == 0) ? x : tab) + c0;
    float4 pfA = *(const float4*)(src);
    float4 pfB = *(const float4*)(src + NN);
    float4 pfC = *(const float4*)(src + 2 * NN);
    float4 pfD = *(const float4*)(src + 3 * NN);
    const float* pl = src + 4 * NN;
    int rown = 4;

    // one DP row; cr/pr/prevEdx/carries captured by reference; no reg arrays
    int cr_ = 0, pr_ = 0;
    float prevEdx = 0.f;
    auto rowF = [&](float4 ev, int k, bool first) {
      float ex0 = ev.x, ex1 = ev.y, ex2 = ev.z, ex3 = ev.w;
      if (MODE == 0) { ex0 = __expf(ex0); ex1 = __expf(ex1); ex2 = __expf(ex2); ex3 = __expf(ex3); }
      const float2 edc = E[cr_][wv][k];
      const float Sr = first ? SinC : prevEdx * escale;
      const float Xi = edc.y * escale;
      prevEdx = edc.x;

      float sh  = __shfl_up(s1_3, 1);
      float sd0 = isL0 ? Sr : sh;
      acc = fmaf(ex0, sd0,  acc);
      acc = fmaf(ex1, s1_0, acc);
      acc = fmaf(ex2, s1_1, acc);
      acc = fmaf(ex3, s1_2, acc);
      float M0 = ex0 * (sd0  + one);
      float M1 = ex1 * (s1_0 + one);
      float M2 = ex2 * (s1_1 + one);
      float M3 = ex3 * (s1_2 + one);

      float Q  = fmaf(cGE, fmaf(cGE, fmaf(cGE, M0, M1), M2), M3);
      float q1 = __shfl_up(Q, 1);
      float q2 = __shfl_up(Q, 2);
      q2 = isL1 ? Xi : q2;
      float X0 = fmaf(C4, q2, q1);
      X0 = isL0 ? Xi : X0;
      float X1 = fmaf(cGE, X0, M0);
      float X2 = fmaf(cGE, X1, M1);
      float X3 = fmaf(cGE, X2, M2);

      float T0 = fmaf(cGO, X0, M0);
      float T1 = fmaf(cGO, X1, M1);
      float T2 = fmaf(cGO, X2, M2);
      float T3 = fmaf(cGO, X3, M3);
      float Y0 = fmaf(cGE, yc0, tg0);
      float Y1 = fmaf(cGE, yc1, tg1);
      float Y2 = fmaf(cGE, yc2, tg2);
      float Y3 = fmaf(cGE, yc3, tg3);
      float S0 = T0 + Y0, S1n = T1 + Y1, S2n = T2 + Y2, S3n = T3 + Y3;
      tmx = fmaxf(tmx, fmaxf(fmaxf(S0, S1n), fmaxf(S2n, S3n)));
      tg0 = cGO * T0; tg1 = cGO * T1; tg2 = cGO * T2; tg3 = cGO * T3;
      yc0 = Y0; yc1 = Y1; yc2 = Y2; yc3 = Y3;
      s1_0 = S0; s1_1 = S1n; s1_2 = S2n; s1_3 = S3n;

      if (isL63) E[pr_][wv + 1][k] = make_float2(S3n, fmaf(C4, X0, Q));
    };

    for (int s = 0; s < NSTEP; ++s) {
      pr_ = s & 1; cr_ = pr_ ^ 1;
      const bool act = (s >= wv) && (s < wv + SPW);
      if (act) {
        prevEdx = 0.f;
        for (int kk = 0; kk < RPS / 4; ++kk) {
          const int kb = kk << 2;
          float4 e0 = pfA, e1 = pfB, e2 = pfC, e3 = pfD;
          if (MODE == 1) {
            pfA = *(const float4*)pl;          pl += NN;
            pfB = *(const float4*)pl;          pl += NN;
            pfC = *(const float4*)pl;          pl += NN;
            pfD = *(const float4*)pl;          pl += NN;
          } else {
            int r0 = (rown     < NN) ? rown     : NN - 1;
            int r1 = (rown + 1 < NN) ? rown + 1 : NN - 1;
            int r2 = (rown + 2 < NN) ? rown + 2 : NN - 1;
            int r3 = (rown + 3 < NN) ? rown + 3 : NN - 1;
            pfA = *(const float4*)(src + (size_t)r0 * NN);
            pfB = *(const float4*)(src + (size_t)r1 * NN);
            pfC = *(const float4*)(src + (size_t)r2 * NN);
            pfD = *(const float4*)(src + (size_t)r3 * NN);
            rown += 4;
          }
          rowF(e0, kb + 0, kk == 0);
          rowF(e1, kb + 1, false);
          rowF(e2, kb + 2, false);
          rowF(e3, kb + 3, false);
        }
        SinC = prevEdx * escale;
      }
      { // per-step shared-exponent rescale (32 rows)
        float m = tmx;
        m = fmaxf(m, __shfl_xor(m, 1));  m = fmaxf(m, __shfl_xor(m, 2));
        m = fmaxf(m, __shfl_xor(m, 4));  m = fmaxf(m, __shfl_xor(m, 8));
        m = fmaxf(m, __shfl_xor(m, 16)); m = fmaxf(m, __shfl_xor(m, 32));
        if (lane == 0) red[pr_][wv] = m;
      }
      __syncthreads();
      {
        float mm = red[pr_][lane & (NW - 1)];
        mm = fmaxf(mm, __shfl_xor(mm, 1));
        mm = fmaxf(mm, __shfl_xor(mm, 2));
        mm = fmaxf(mm, __shfl_xor(mm, 4));
        tmx = 0.f; escale = 1.f;
        int e = (mm > 0.f) ? ilogbf(mm) : 0;
        if (e > 126) e = 126; if (e < -126) e = -126;
        if (e != 0) {
          const float c = ldexpf(1.f, -e);
          s1_0*=c; s1_1*=c; s1_2*=c; s1_3*=c;
          tg0*=c; tg1*=c; tg2*=c; tg3*=c;
          yc0*=c; yc1*=c; yc2*=c; yc3*=c;
          acc*=c; one*=c; SinC*=c;
          escale = c; Etot += e;
        }
      }
    }
    float ssum = acc;
    ssum += __shfl_xor(ssum, 1);  ssum += __shfl_xor(ssum, 2);
    ssum += __shfl_xor(ssum, 4);  ssum += __shfl_xor(ssum, 8);
    ssum += __shfl_xor(ssum, 16); ssum += __shfl_xor(ssum, 32);
    if (lane == 0) wsum[wv] = ssum;
    __syncthreads();
    if (MODE == 0) {
      if (tid == 0) {
        double tot = 0.0;
        #pragma unroll
        for (int k = 0; k < NW; ++k) tot += (double)wsum[k];
        out[0] = (float)(log(tot) + (double)Etot * LN2);
      }
    } else {
      *(float4*)(arr + c0)          = make_float4(s1_0, s1_1, s1_2, s1_3);  // S[1023,b]
      *(float4*)(arr + NN + c0)     = make_float4(tg0, tg1, tg2, tg3);      // cGO*T[1023,b]
      *(float4*)(arr + 2 * NN + c0) = make_float4(yc0, yc1, yc2, yc3);      // Y[1023,b]
      if (tid == 0) {
        float t = 0.f;
        #pragma unroll
        for (int k = 0; k < NW; ++k) t += wsum[k];
        arr[5 * NN + 0] = t;                     // acc_top (units 2^E0)
        ((int*)(arr + 5 * NN))[2] = Etot;        // E0
      }
    }
  } else {
    // ======================= BACKWARD (adjoint, mirrored cols) =======================
    const int SPWB = 1024 / RPS;
    float gM1_0=0.f,gM1_1=0.f,gM1_2=0.f,gM1_3=0.f;
    float gY1_0=0.f,gY1_1=0.f,gY1_2=0.f,gY1_3=0.f;
    float accB=0.f, one=1.f, tmx=0.f, escale=1.f, gMinC=0.f;
    int Etot = 0;
    const float* src = tabR + c0;
    float4 pfA = *(const float4*)(src);
    float4 pfB = *(const float4*)(src + NN);
    float4 pfC = *(const float4*)(src + 2 * NN);
    float4 pfD = *(const float4*)(src + 3 * NN);
    const float* pl = src + 4 * NN;

    int cr_ = 0, pr_ = 0;
    float prevEdx = 0.f;
    auto rowB = [&](float4 ev, int k, bool first) {
      const float er0 = ev.x, er1 = ev.y, er2 = ev.z, er3 = ev.w;
      const float2 edc = E[cr_][wv][k];
      const float gMdIn = first ? gMinC : prevEdx * escale;
      const float Xi = edc.y * escale;
      prevEdx = edc.x;

      float gmh  = __shfl_up(gM1_3, 1);
      float gMd0 = isL0 ? gMdIn : gmh;
      float gMd1 = gM1_0, gMd2 = gM1_1, gMd3 = gM1_2;
      accB = fmaf(er0, gMd0, accB);
      accB = fmaf(er1, gMd1, accB);
      accB = fmaf(er2, gMd2, accB);
      accB = fmaf(er3, gMd3, accB);
      float a0 = er0 * (gMd0 + one);
      float a1 = er1 * (gMd1 + one);
      float a2 = er2 * (gMd2 + one);
      float a3 = er3 * (gMd3 + one);

      float gTs0 = fmaf(cGO, gY1_0, a0);
      float gTs1 = fmaf(cGO, gY1_1, a1);
      float gTs2 = fmaf(cGO, gY1_2, a2);
      float gTs3 = fmaf(cGO, gY1_3, a3);
      float gY0n = fmaf(cGE, gY1_0, a0);
      float gY1n = fmaf(cGE, gY1_1, a1);
      float gY2n = fmaf(cGE, gY1_2, a2);
      float gY3n = fmaf(cGE, gY1_3, a3);

      float Qg = fmaf(cGE, fmaf(cGE, fmaf(cGE, gTs0, gTs1), gTs2), gTs3);
      float q1 = __shfl_up(Qg, 1);
      float q2 = __shfl_up(Qg, 2);
      q2 = isL1 ? Xi : q2;
      float gXin = fmaf(C4, q2, q1);
      gXin = isL0 ? Xi : gXin;
      float gX0 = fmaf(cGE, gXin, gTs0);
      float gX1 = fmaf(cGE, gX0,  gTs1);
      float gX2 = fmaf(cGE, gX1,  gTs2);
      float gM0n = fmaf(cGO, gXin, gTs0);
      float gM1n = fmaf(cGO, gX0,  gTs1);
      float gM2n = fmaf(cGO, gX1,  gTs2);
      float gM3n = fmaf(cGO, gX2,  gTs3);

      tmx = fmaxf(tmx, fmaxf(fmaxf(gM0n, gM1n), fmaxf(gM2n, gM3n)));
      tmx = fmaxf(tmx, fmaxf(fmaxf(gY0n, gY1n), fmaxf(gY2n, gY3n)));
      gM1_0 = gM0n; gM1_1 = gM1n; gM1_2 = gM2n; gM1_3 = gM3n;
      gY1_0 = gY0n; gY1_1 = gY1n; gY1_2 = gY2n; gY1_3 = gY3n;

      if (isL63) E[pr_][wv + 1][k] = make_float2(gM3n, fmaf(C4, gXin, Qg));
    };

    const int NSTEPB = SPWB + NW - 1 + 1;        // +1: epilogue row (es row 1024)
    for (int s = 0; s < NSTEPB; ++s) {
      pr_ = s & 1; cr_ = pr_ ^ 1;
      const bool actM = (s >= wv) && (s < wv + SPWB);
      const bool actE = (s == wv + SPWB);
      if (actM) {
        prevEdx = 0.f;
        for (int kk = 0; kk < RPS / 4; ++kk) {
          const int kb = kk << 2;
          float4 e0 = pfA, e1 = pfB, e2 = pfC, e3 = pfD;
          pfA = *(const float4*)pl;            pl += NN;
          pfB = *(const float4*)pl;            pl += NN;
          pfC = *(const float4*)pl;            pl += NN;
          pfD = *(const float4*)pl;            pl += NN;
          rowB(e0, kb + 0, kk == 0);
          rowB(e1, kb + 1, false);
          rowB(e2, kb + 2, false);
          rowB(e3, kb + 3, false);
        }
        gMinC = prevEdx * escale;
      } else if (actE) {
        // epilogue: accB += es[1024,.] * gM[1024,.]  (tabR row 1024 = pfA)
        float gmh  = __shfl_up(gM1_3, 1);
        float gMd0 = isL0 ? gMinC : gmh;
        accB = fmaf(pfA.x, gMd0,  accB);
        accB = fmaf(pfA.y, gM1_0, accB);
        accB = fmaf(pfA.z, gM1_1, accB);
        accB = fmaf(pfA.w, gM1_2, accB);
      }
      { // rescale (carries stay live to the end)
        float m = tmx;
        m = fmaxf(m, __shfl_xor(m, 1));  m = fmaxf(m, __shfl_xor(m, 2));
        m = fmaxf(m, __shfl_xor(m, 4));  m = fmaxf(m, __shfl_xor(m, 8));
        m = fmaxf(m, __shfl_xor(m, 16)); m = fmaxf(m, __shfl_xor(m, 32));
        if (lane == 0) red[pr_][wv] = m;
      }
      __syncthreads();
      {
        float mm = red[pr_][lane & (NW - 1)];
        mm = fmaxf(mm, __shfl_xor(mm, 1));
        mm = fmaxf(mm, __shfl_xor(mm, 2));
        mm = fmaxf(mm, __shfl_xor(mm, 4));
        tmx = 0.f; escale = 1.f;
        int e = (mm > 0.f) ? ilogbf(mm) : 0;
        if (e > 126) e = 126; if (e < -126) e = -126;
        if (e != 0) {
          const float c = ldexpf(1.f, -e);
          gM1_0*=c; gM1_1*=c; gM1_2*=c; gM1_3*=c;
          gY1_0*=c; gY1_1*=c; gY1_2*=c; gY1_3*=c;
          accB*=c; one*=c; gMinC*=c;
          escale = c; Etot += e;
        }
      }
    }
    // write gM[1024,b], gY[1024,b]  (b = 2047-c -> reversed float4)
    *(float4*)(arr + 3 * NN + (2044 - c0)) = make_float4(gM1_3, gM1_2, gM1_1, gM1_0);
    *(float4*)(arr + 4 * NN + (2044 - c0)) = make_float4(gY1_3, gY1_2, gY1_1, gY1_0);
    float ssum = accB;
    ssum += __shfl_xor(ssum, 1);  ssum += __shfl_xor(ssum, 2);
    ssum += __shfl_xor(ssum, 4);  ssum += __shfl_xor(ssum, 8);
    ssum += __shfl_xor(ssum, 16); ssum += __shfl_xor(ssum, 32);
    if (lane == 0) wsum[wv] = ssum;
    __syncthreads();
    if (tid == 0) {
      float t = 0.f;
      #pragma unroll
      for (int k = 0; k < NW; ++k) t += wsum[k];
      arr[5 * NN + 1] = t;                       // acc_b0 (units 2^E1)
      ((int*)(arr + 5 * NN))[3] = Etot;          // E1
    }
  }
}

// ---------------------------------------------------------------------------
// Combine (unchanged): three exponent groups
//   A0 (2^E0) = acc_top + sum_b es[1024,b+1]*S[1023,b] ;  A1 (2^E1) = acc_b0
//   A01 (2^E0+E1) = sum_b es[1024,b+1]*gM[1024,b+1]*S[1023,b]
//                 + sum_b gY[1024,b]*(cGO*T[1023,b] + cGE*Y[1023,b])
// ---------------------------------------------------------------------------
__global__ __launch_bounds__(1024)
void combine_kernel(const float* __restrict__ tab, const float* __restrict__ arr,
                    float* __restrict__ out) {
  __shared__ double sh01[16], sh0[16];
  const int tid = threadIdx.x, lane = tid & 63, wv = tid >> 6;
  const float cGE = 0.36787944117144233f;
  double t01 = 0.0, t0 = 0.0;
  for (int b = tid; b < NN; b += 1024) {
    const float S  = arr[b];
    const float tg = arr[NN + b];
    const float yc = arr[2 * NN + b];
    const float gY = arr[4 * NN + b];
    t01 += (double)gY * ((double)tg + (double)cGE * (double)yc);
    if (b < NN - 1) {
      const float es = tab[(size_t)1024 * NN + b + 1];
      const float gM = arr[3 * NN + b + 1];
      t01 += (double)es * (double)gM * (double)S;
      t0  += (double)es * (double)S;
    }
  }
  #pragma unroll
  for (int off = 1; off < 64; off <<= 1) {
    t01 += __shfl_xor(t01, off);
    t0  += __shfl_xor(t0, off);
  }
  if (lane == 0) { sh01[wv] = t01; sh0[wv] = t0; }
  __syncthreads();
  if (tid == 0) {
    double A01 = 0.0, A0 = 0.0;
    #pragma unroll
    for (int k = 0; k < 16; ++k) { A01 += sh01[k]; A0 += sh0[k]; }
    const float* resF = arr + 5 * NN;
    const float accTop = resF[0], accB = resF[1];
    const int E0 = ((const int*)resF)[2], E1 = ((const int*)resF)[3];
    A0 += (double)accTop;
    const double A1 = (double)accB;
    const long long e01 = (long long)E0 + (long long)E1;
    long long em = e01;
    if ((long long)E0 > em) em = E0;
    if ((long long)E1 > em) em = E1;
    const double tot = A01 * exp2((double)(e01 - em))
                     + A0  * exp2((double)((long long)E0 - em))
                     + A1  * exp2((double)((long long)E1 - em));
    out[0] = (float)(log(tot) + (double)em * LN2);
  }
}

extern "C" void kernel_launch(void* const* d_in, const int* in_sizes, int n_in,
                              void* d_out, int out_size, void* d_ws, size_t ws_size,
                              hipStream_t stream) {
  const float* x = (const float*)d_in[0];
  float* out = (float*)d_out;
  const size_t need = ((size_t)2 * TROWS * NN + 5 * NN + 16) * sizeof(float);
  if (ws_size >= need) {
    float* tab  = (float*)d_ws;
    float* tabR = tab + (size_t)TROWS * NN;
    float* arr  = tab + (size_t)2 * TROWS * NN;
    prep_kernel<<<dim3(NN / 256, TROWS), dim3(256), 0, stream>>>(x, tab, tabR);
    sw2_kernel<1><<<dim3(2), dim3(NW * 64), 0, stream>>>(x, tab, tabR, arr, out);
    combine_kernel<<<dim3(1), dim3(1024), 0, stream>>>(tab, arr, out);
  } else {
    sw2_kernel<0><<<dim3(1), dim3(NW * 64), 0, stream>>>(x, nullptr, nullptr, nullptr, out);
  }
}